// Round 1
// baseline (492.032 us; speedup 1.0000x reference)
//
#include <hip/hip_runtime.h>
#include <math.h>

#define Bn 128
#define Tn 16
#define TOn 32
#define Jn 25
#define INn 256
#define OUTn 512
#define Hn 8
#define NEGC (-1000000000.0f)

// ---------------------------------------------------------------------------
// Index algebra (see R1 notes): reshape (B,TO,J,OUT)->(B,H,TO,J,hid) maps
// (h,p',j',c) -> orig row p = kmul*h + (p'>>3), g = 25*(p'&7)+j', j=g>>3,
// o = 64*(g&7)+c.  hs=32.  Simplifications:
//  - q,k only used as channel-sums -> pre-reduced weights (k_wsum/k_lowsum)
//  - softmax(attn_t).sum(-1)==1 -> x_t = sum_t v_t (q_t,k_t,mask_t dead)
//  - V reduced per (b,t) to P[8][32], U[25][32]; vt[b][h] = U[2h]+U[2h+1]
// R2: V-GEMM via bf16 MFMA 32x32x16; enc bf16 staged in d_out scratch.
// R3: fix vt batch stride in k_final (b*6400, was b*51200 -> OOB garbage).
// R4 (this round): dispatch-count fusion 8 -> 4 kernels.
//  - k_prep       = k_wsum + k_wvbf16 (grid split)
//  - k_lowsum2    = both lowsum passes (x and enc) in one launch
//  - k_vgemm      unchanged
//  - k_final2     = k_vt + k_convsum + k_final; vt/vssum/kssum buffers gone
//    (each (b,to) block stages P[16][256] + klow[16][200] in LDS, computes
//     its own conv contraction, reads U row-pairs directly for temporal half)
// ---------------------------------------------------------------------------

// ws layout (float offsets)
#define OFF_WQSUM 0          // 2048
#define OFF_WKSUM 2048       // 2048
#define OFF_BQSUM 4096       // 8
#define OFF_BKSUM 4104       // 8
#define OFF_WVB   4112       // 131072 shorts = 65536 floats
#define OFF_QLOW  69648      // 128*32*200
#define OFF_KLOW  888848     // 128*16*200
#define OFF_P     1298448    // 128*16*256
#define OFF_U     1822736    // 128*16*800
// total used 3461136 floats = 13.8 MB

typedef __attribute__((ext_vector_type(8))) short s16x8;
typedef __attribute__((ext_vector_type(16))) float f32x16;

__device__ inline short f2bf(float f) {
    union { float f; unsigned u; } v; v.f = f;
    unsigned r = v.u + 0x7fffu + ((v.u >> 16) & 1u);
    return (short)(r >> 16);
}

// blocks 0..15: pre-reduced Wq/Wk row sums; blocks 16..527: Wv -> bf16
__global__ void k_prep(const float* __restrict__ Wq, const float* __restrict__ bq,
                       const float* __restrict__ Wk, const float* __restrict__ bk,
                       const float* __restrict__ Wv, short* __restrict__ Wvb,
                       float* __restrict__ ws) {
    int bid = blockIdx.x;
    if (bid < 16) {
        int mat = bid >> 3, u = bid & 7, k = threadIdx.x;
        const float* W  = mat ? Wk : Wq;
        const float* bb = mat ? bk : bq;
        float* wout = ws + (mat ? OFF_WKSUM : OFF_WQSUM);
        float* bout = ws + (mat ? OFF_BKSUM : OFF_BQSUM);
        float s = 0.f;
        for (int i = 0; i < 32; ++i) s += W[(u * 64 + i) * 256 + k];
        wout[u * 256 + k] = s;
        if (k == 0) {
            float sb = 0.f;
            for (int i = 0; i < 32; ++i) sb += bb[u * 64 + i];
            bout[u] = sb;
        }
    } else {
        int idx = (bid - 16) * 256 + threadIdx.x;   // 131072
        Wvb[idx] = f2bf(Wv[idx]);
    }
}

// rows of 256 floats -> 8 half-chunk sums per row; enc part also emits bf16.
// blocks [0,2048): x -> qlow;  blocks [2048,3072): enc -> klow + encb.
__global__ void k_lowsum2(const float* __restrict__ x, const float* __restrict__ enc,
                          const float* __restrict__ ws, float* __restrict__ qlow,
                          float* __restrict__ klow, short* __restrict__ encb) {
    int bid = blockIdx.x;
    int lane = threadIdx.x & 63;
    int wave = threadIdx.x >> 6;
    bool isx = bid < 2048;
    const float* X    = isx ? x : enc;
    const float* wsum = ws + (isx ? OFF_WQSUM : OFF_WKSUM);
    const float* bsum = ws + (isx ? OFF_BQSUM : OFF_BKSUM);
    float* out = isx ? qlow : klow;
    short* eb  = isx ? (short*)nullptr : encb;
    int nrows  = isx ? (Bn * TOn * Jn) : (Bn * Tn * Jn);
    int b0     = isx ? bid : bid - 2048;
    int stride = (isx ? 2048 : 1024) * 4;

    float4 w[8];
#pragma unroll
    for (int u = 0; u < 8; ++u) w[u] = *(const float4*)(wsum + u * 256 + lane * 4);
    float bs[8];
#pragma unroll
    for (int u = 0; u < 8; ++u) bs[u] = bsum[u];

    for (int row = b0 * 4 + wave; row < nrows; row += stride) {
        float4 xv = *(const float4*)(X + (size_t)row * 256 + lane * 4);
        if (eb) {
            short4 sv;
            sv.x = f2bf(xv.x); sv.y = f2bf(xv.y); sv.z = f2bf(xv.z); sv.w = f2bf(xv.w);
            *(short4*)(eb + (size_t)row * 256 + lane * 4) = sv;
        }
        float p[8];
#pragma unroll
        for (int u = 0; u < 8; ++u)
            p[u] = xv.x * w[u].x + xv.y * w[u].y + xv.z * w[u].z + xv.w * w[u].w;
#pragma unroll
        for (int m = 1; m < 64; m <<= 1) {
#pragma unroll
            for (int u = 0; u < 8; ++u) p[u] += __shfl_xor(p[u], m, 64);
        }
        if (lane == 0) {
            float4 o0 = {p[0] + bs[0], p[1] + bs[1], p[2] + bs[2], p[3] + bs[3]};
            float4 o1 = {p[4] + bs[4], p[5] + bs[5], p[6] + bs[6], p[7] + bs[7]};
            float4* op = (float4*)(out + (size_t)row * 8);
            op[0] = o0; op[1] = o1;
        }
    }
}

// per (b,t): V(25x512) = enc(25x256) @ Wv^T via bf16 MFMA, reduced to P, U
__global__ __launch_bounds__(256) void k_vgemm(const short* __restrict__ encb,
                                               const short* __restrict__ Wvb,
                                               const float* __restrict__ bv,
                                               float* __restrict__ P,
                                               float* __restrict__ U) {
    __shared__ float Vs[25 * 520];   // 52 KB, stride 520 kills bank conflicts
    int bt = blockIdx.x;             // b*16 + t
    int tid = threadIdx.x, lane = tid & 63, wave = tid >> 6;
    int m = lane & 31;               // A row / B col within tile
    int kq = (lane >> 5) * 8;        // k sub-offset (0 or 8)
    bool mok = (m < 25);
    const short* aptr = encb + (size_t)bt * 6400 + m * 256 + kq;
    int n0 = wave * 4;               // 4 n-tiles of 32 per wave
    const short* bptr[4];
#pragma unroll
    for (int t = 0; t < 4; ++t)
        bptr[t] = Wvb + ((n0 + t) * 32 + m) * 256 + kq;

    f32x16 acc[4];
#pragma unroll
    for (int t = 0; t < 4; ++t)
#pragma unroll
        for (int r = 0; r < 16; ++r) acc[t][r] = 0.f;

    const s16x8 za = (s16x8)(short)0;
#pragma unroll 4
    for (int ks = 0; ks < 16; ++ks) {
        s16x8 afrag = za;
        if (mok) afrag = *(const s16x8*)(aptr + ks * 16);
#pragma unroll
        for (int t = 0; t < 4; ++t) {
            s16x8 bfrag = *(const s16x8*)(bptr[t] + ks * 16);
            acc[t] = __builtin_amdgcn_mfma_f32_32x32x16_bf16(afrag, bfrag, acc[t], 0, 0, 0);
        }
    }

    // C/D layout: col = lane&31, row = (reg&3) + 8*(reg>>2) + 4*(lane>>5)
    int rbase = 4 * (lane >> 5);
#pragma unroll
    for (int t = 0; t < 4; ++t) {
        int col = (n0 + t) * 32 + (lane & 31);
        float bvv = bv[col];
#pragma unroll
        for (int r = 0; r < 16; ++r) {
            int row = (r & 3) + 8 * (r >> 2) + rbase;
            if (row < 25) Vs[row * 520 + col] = acc[t][r] + bvv;
        }
    }
    __syncthreads();
    {   // P: 256 slots
        int a = tid >> 5, c = tid & 31;
        float sum = 0.f;
        for (int g = 25 * a; g < 25 * a + 25; ++g)
            sum += Vs[(g >> 3) * 520 + ((g & 7) << 6) + c];
        P[(size_t)bt * 256 + tid] = sum;
    }
    for (int s = tid; s < 800; s += 256) {   // U: 800 slots
        int jp = s >> 5, c = s & 31;
        float sum = 0.f;
#pragma unroll
        for (int a = 0; a < 8; ++a) {
            int g = 25 * a + jp;
            sum += Vs[(g >> 3) * 520 + ((g & 7) << 6) + 32 + c];
        }
        U[(size_t)bt * 800 + s] = sum;
    }
}

// per (b,to'): conv contraction + masked rank-1 softmax diagonal + output.
// Replaces k_vt + k_convsum + k_final: stages this b's P (16x256) and klow
// (16x200) in LDS, computes kssum/vssum rows for its own `to`, and reads
// U row-pairs directly for the temporal half.
__global__ __launch_bounds__(256) void k_final2(const float* __restrict__ qlow,
                        const float* __restrict__ klow,
                        const float* __restrict__ P, const float* __restrict__ U,
                        const float* __restrict__ Wconv, const float* __restrict__ bconv,
                        const int* __restrict__ mask_s, float* __restrict__ out) {
    __shared__ float Pall[4096];     // P rows b*16+t, t=0..15 (16 KB)
    __shared__ float Kl[3200];       // klow rows b*16+t, t=0..15 (12.8 KB)
    __shared__ float qv[200], kv[200], vsl[8 * 36], dg[200];
    __shared__ float Wc[16];
    __shared__ float bcv;
    __shared__ int msk[625];
    int blk = blockIdx.x;            // b*32 + top
    int b = blk >> 5, top = blk & 31;
    int tid = threadIdx.x;           // 256

    {   // stage
        const float4* Ps = (const float4*)(P + (size_t)b * 4096);
        float4* Pd = (float4*)Pall;
        for (int s = tid; s < 1024; s += 256) Pd[s] = Ps[s];
        const float4* Ks = (const float4*)(klow + (size_t)b * 3200);
        float4* Kd = (float4*)Kl;
        for (int s = tid; s < 800; s += 256) Kd[s] = Ks[s];
        for (int s = tid; s < 625; s += 256) msk[s] = mask_s[top * 625 + s];
        if (tid < 16) Wc[tid] = Wconv[top * 16 + tid];
        if (tid == 0) bcv = bconv[top];
        if (tid < 200) {
            int h = tid / 25, i = tid - 25 * (tid / 25);
            qv[tid] = qlow[((size_t)b * 32 + 4 * h + (top >> 3)) * 200 + 25 * (top & 7) + i];
        }
    }
    __syncthreads();

    {   // vssum row for this to: vsl[h][c], h=tid>>5, c=tid&31 (exactly 256)
        int h = tid >> 5, c = tid & 31;
        float s = 25.f * bcv;
#pragma unroll
        for (int tp = 0; tp < 16; ++tp)
            s += Wc[tp] * Pall[(2 * h + (tp >> 3)) * 256 + (tp & 7) * 32 + c];
        vsl[h * 36 + c] = s;
    }
    if (tid < 200) {   // kssum row for this to: kv[h*25+i]
        int h = tid / 25, i = tid - 25 * (tid / 25);
        float s = 32.f * bcv;
#pragma unroll
        for (int tp = 0; tp < 16; ++tp)
            s += Wc[tp] * Kl[(2 * h + (tp >> 3)) * 200 + 25 * (tp & 7) + i];
        kv[tid] = s;
    }
    __syncthreads();

    if (tid < 200) {   // masked rank-1 softmax diagonal
        int h = tid / 25, i = tid - 25 * (tid / 25);
        float q = qv[tid];
        float m = -3.0e38f;
#pragma unroll
        for (int j = 0; j < 25; ++j) {
            float a = msk[i * 25 + j] ? q * kv[h * 25 + j] : NEGC;
            m = fmaxf(m, a);
        }
        float sum = 0.f;
#pragma unroll
        for (int j = 0; j < 25; ++j) {
            float a = msk[i * 25 + j] ? q * kv[h * 25 + j] : NEGC;
            sum += expf(a - m);
        }
        float ai = msk[i * 25 + i] ? q * kv[h * 25 + i] : NEGC;
        dg[tid] = expf(ai - m) / sum;
    }
    __syncthreads();

    float4* outp = (float4*)(out + (size_t)blk * 12800);
    const float4* U4 = (const float4*)U;
    for (int q = tid; q < 3200; q += 256) {   // q = i*128 + o4
        int i = q >> 7, o4 = q & 127, h = o4 >> 4, e = o4 & 15;
        float4 r;
        if (e < 8) {            // spatial half: c = 4e
            float d = dg[h * 25 + i];
            const float* vp = &vsl[h * 36 + 4 * e];
            r.x = d * vp[0]; r.y = d * vp[1]; r.z = d * vp[2]; r.w = d * vp[3];
        } else {                // temporal half: vt = U[2h] + U[2h+1]
            size_t u0 = ((size_t)b * 16 + 2 * h) * 200 + i * 8 + (e - 8);
            float4 a0 = U4[u0];
            float4 a1 = U4[u0 + 200];
            r.x = a0.x + a1.x; r.y = a0.y + a1.y;
            r.z = a0.z + a1.z; r.w = a0.w + a1.w;
        }
        outp[q] = r;
    }
}

extern "C" void kernel_launch(void* const* d_in, const int* in_sizes, int n_in,
                              void* d_out, int out_size, void* d_ws, size_t ws_size,
                              hipStream_t stream) {
    const float* x      = (const float*)d_in[0];
    const float* enc    = (const float*)d_in[1];
    const int*   mask_s = (const int*)d_in[2];
    // d_in[3] = mask_t: dead
    const float* Wq     = (const float*)d_in[4];
    const float* bq     = (const float*)d_in[5];
    const float* Wk     = (const float*)d_in[6];
    const float* bk     = (const float*)d_in[7];
    const float* Wv     = (const float*)d_in[8];
    const float* bv     = (const float*)d_in[9];
    const float* Wconv  = (const float*)d_in[10];
    const float* bconv  = (const float*)d_in[11];
    float* out = (float*)d_out;
    float* ws  = (float*)d_ws;

    short* Wvb   = (short*)(ws + OFF_WVB);
    float* qlow  = ws + OFF_QLOW;
    float* klow  = ws + OFF_KLOW;
    float* Pbuf  = ws + OFF_P;
    float* Ubuf  = ws + OFF_U;
    // enc in bf16 staged in d_out (209 MB, fully overwritten by k_final2 later)
    short* encb  = (short*)d_out;

    hipLaunchKernelGGL(k_prep, dim3(528), dim3(256), 0, stream,
                       Wq, bq, Wk, bk, Wv, Wvb, ws);
    hipLaunchKernelGGL(k_lowsum2, dim3(3072), dim3(256), 0, stream,
                       x, enc, ws, qlow, klow, encb);
    hipLaunchKernelGGL(k_vgemm, dim3(Bn * Tn), dim3(256), 0, stream,
                       encb, Wvb, bv, Pbuf, Ubuf);
    hipLaunchKernelGGL(k_final2, dim3(Bn * TOn), dim3(256), 0, stream,
                       qlow, klow, Pbuf, Ubuf, Wconv, bconv, mask_s, out);
}

// Round 2
// 489.979 us; speedup vs baseline: 1.0042x; 1.0042x over previous
//
#include <hip/hip_runtime.h>
#include <math.h>

#define Bn 128
#define Tn 16
#define TOn 32
#define Jn 25
#define INn 256
#define OUTn 512
#define Hn 8
#define NEGC (-1000000000.0f)

// ---------------------------------------------------------------------------
// Index algebra (see R1 notes): reshape (B,TO,J,OUT)->(B,H,TO,J,hid) maps
// (h,p',j',c) -> orig row p = kmul*h + (p'>>3), g = 25*(p'&7)+j', j=g>>3,
// o = 64*(g&7)+c.  hs=32.  Simplifications:
//  - q,k only used as channel-sums -> pre-reduced weights (k_wsum/k_lowsum)
//  - softmax(attn_t).sum(-1)==1 -> x_t = sum_t v_t (q_t,k_t,mask_t dead)
//  - V reduced per (b,t) to P[8][32], U[25][32]; vt[b][h] = U[2h]+U[2h+1]
// R2: V-GEMM via bf16 MFMA 32x32x16; enc bf16 staged in d_out scratch.
// R3: fix vt batch stride in k_final (b*6400, was b*51200 -> OOB garbage).
// R4: dispatch-count fusion 8 -> 4 kernels (null: window is harness-floor
//     dominated; ~2 large poison fills + misc resets ≈ 380 µs of the window).
// R5 (this round): k_vgemm processes G=4 bt per block (grid 512). Wvb is
//     256 KB and was re-read in full by every one of 2048 blocks = 512 MB
//     of L2 traffic (~15 µs @ 34.5 TB/s) vs 1.7 µs of MFMA. B-fragments are
//     identical across g, so per-block Wvb reads amortize 4x -> ~128 MB.
//     2 blocks/CU retained for latency hiding; reduce phase of tile g
//     overlaps MFMA of tile g+1 across waves (2 barriers per g).
// ---------------------------------------------------------------------------

// ws layout (float offsets)
#define OFF_WQSUM 0          // 2048
#define OFF_WKSUM 2048       // 2048
#define OFF_BQSUM 4096       // 8
#define OFF_BKSUM 4104       // 8
#define OFF_WVB   4112       // 131072 shorts = 65536 floats
#define OFF_QLOW  69648      // 128*32*200
#define OFF_KLOW  888848     // 128*16*200
#define OFF_P     1298448    // 128*16*256
#define OFF_U     1822736    // 128*16*800
// total used 3461136 floats = 13.8 MB

typedef __attribute__((ext_vector_type(8))) short s16x8;
typedef __attribute__((ext_vector_type(16))) float f32x16;

__device__ inline short f2bf(float f) {
    union { float f; unsigned u; } v; v.f = f;
    unsigned r = v.u + 0x7fffu + ((v.u >> 16) & 1u);
    return (short)(r >> 16);
}

// blocks 0..15: pre-reduced Wq/Wk row sums; blocks 16..527: Wv -> bf16
__global__ void k_prep(const float* __restrict__ Wq, const float* __restrict__ bq,
                       const float* __restrict__ Wk, const float* __restrict__ bk,
                       const float* __restrict__ Wv, short* __restrict__ Wvb,
                       float* __restrict__ ws) {
    int bid = blockIdx.x;
    if (bid < 16) {
        int mat = bid >> 3, u = bid & 7, k = threadIdx.x;
        const float* W  = mat ? Wk : Wq;
        const float* bb = mat ? bk : bq;
        float* wout = ws + (mat ? OFF_WKSUM : OFF_WQSUM);
        float* bout = ws + (mat ? OFF_BKSUM : OFF_BQSUM);
        float s = 0.f;
        for (int i = 0; i < 32; ++i) s += W[(u * 64 + i) * 256 + k];
        wout[u * 256 + k] = s;
        if (k == 0) {
            float sb = 0.f;
            for (int i = 0; i < 32; ++i) sb += bb[u * 64 + i];
            bout[u] = sb;
        }
    } else {
        int idx = (bid - 16) * 256 + threadIdx.x;   // 131072
        Wvb[idx] = f2bf(Wv[idx]);
    }
}

// rows of 256 floats -> 8 half-chunk sums per row; enc part also emits bf16.
// blocks [0,2048): x -> qlow;  blocks [2048,3072): enc -> klow + encb.
__global__ void k_lowsum2(const float* __restrict__ x, const float* __restrict__ enc,
                          const float* __restrict__ ws, float* __restrict__ qlow,
                          float* __restrict__ klow, short* __restrict__ encb) {
    int bid = blockIdx.x;
    int lane = threadIdx.x & 63;
    int wave = threadIdx.x >> 6;
    bool isx = bid < 2048;
    const float* X    = isx ? x : enc;
    const float* wsum = ws + (isx ? OFF_WQSUM : OFF_WKSUM);
    const float* bsum = ws + (isx ? OFF_BQSUM : OFF_BKSUM);
    float* out = isx ? qlow : klow;
    short* eb  = isx ? (short*)nullptr : encb;
    int nrows  = isx ? (Bn * TOn * Jn) : (Bn * Tn * Jn);
    int b0     = isx ? bid : bid - 2048;
    int stride = (isx ? 2048 : 1024) * 4;

    float4 w[8];
#pragma unroll
    for (int u = 0; u < 8; ++u) w[u] = *(const float4*)(wsum + u * 256 + lane * 4);
    float bs[8];
#pragma unroll
    for (int u = 0; u < 8; ++u) bs[u] = bsum[u];

    for (int row = b0 * 4 + wave; row < nrows; row += stride) {
        float4 xv = *(const float4*)(X + (size_t)row * 256 + lane * 4);
        if (eb) {
            short4 sv;
            sv.x = f2bf(xv.x); sv.y = f2bf(xv.y); sv.z = f2bf(xv.z); sv.w = f2bf(xv.w);
            *(short4*)(eb + (size_t)row * 256 + lane * 4) = sv;
        }
        float p[8];
#pragma unroll
        for (int u = 0; u < 8; ++u)
            p[u] = xv.x * w[u].x + xv.y * w[u].y + xv.z * w[u].z + xv.w * w[u].w;
#pragma unroll
        for (int m = 1; m < 64; m <<= 1) {
#pragma unroll
            for (int u = 0; u < 8; ++u) p[u] += __shfl_xor(p[u], m, 64);
        }
        if (lane == 0) {
            float4 o0 = {p[0] + bs[0], p[1] + bs[1], p[2] + bs[2], p[3] + bs[3]};
            float4 o1 = {p[4] + bs[4], p[5] + bs[5], p[6] + bs[6], p[7] + bs[7]};
            float4* op = (float4*)(out + (size_t)row * 8);
            op[0] = o0; op[1] = o1;
        }
    }
}

// per block: G=4 consecutive bt tiles. For each: V(25x512) = enc(25x256) @
// Wv^T via bf16 MFMA, reduced to P, U. B-fragments identical across g ->
// Wvb L2 traffic amortizes 4x.
#define VG 4
__global__ __launch_bounds__(256) void k_vgemm(const short* __restrict__ encb,
                                               const short* __restrict__ Wvb,
                                               const float* __restrict__ bv,
                                               float* __restrict__ P,
                                               float* __restrict__ U) {
    __shared__ float Vs[25 * 520];   // 52 KB, stride 520 kills bank conflicts
    int tid = threadIdx.x, lane = tid & 63, wave = tid >> 6;
    int m = lane & 31;               // A row / B col within tile
    int kq = (lane >> 5) * 8;        // k sub-offset (0 or 8)
    bool mok = (m < 25);
    int n0 = wave * 4;               // 4 n-tiles of 32 per wave
    const short* bptr[4];
#pragma unroll
    for (int t = 0; t < 4; ++t)
        bptr[t] = Wvb + ((n0 + t) * 32 + m) * 256 + kq;

    // hoist bias + C-layout constants (identical across g)
    int rbase = 4 * (lane >> 5);
    float bvv[4];
    int colv[4];
#pragma unroll
    for (int t = 0; t < 4; ++t) {
        colv[t] = (n0 + t) * 32 + (lane & 31);
        bvv[t] = bv[colv[t]];
    }

    const s16x8 za = (s16x8)(short)0;
    for (int g = 0; g < VG; ++g) {
        int bt = blockIdx.x * VG + g;
        const short* aptr = encb + (size_t)bt * 6400 + m * 256 + kq;

        f32x16 acc[4];
#pragma unroll
        for (int t = 0; t < 4; ++t)
#pragma unroll
            for (int r = 0; r < 16; ++r) acc[t][r] = 0.f;

#pragma unroll 4
        for (int ks = 0; ks < 16; ++ks) {
            s16x8 afrag = za;
            if (mok) afrag = *(const s16x8*)(aptr + ks * 16);
#pragma unroll
            for (int t = 0; t < 4; ++t) {
                s16x8 bfrag = *(const s16x8*)(bptr[t] + ks * 16);
                acc[t] = __builtin_amdgcn_mfma_f32_32x32x16_bf16(afrag, bfrag, acc[t], 0, 0, 0);
            }
        }

        if (g) __syncthreads();      // prior reduce must be done reading Vs
        // C/D layout: col = lane&31, row = (reg&3) + 8*(reg>>2) + 4*(lane>>5)
#pragma unroll
        for (int t = 0; t < 4; ++t) {
#pragma unroll
            for (int r = 0; r < 16; ++r) {
                int row = (r & 3) + 8 * (r >> 2) + rbase;
                if (row < 25) Vs[row * 520 + colv[t]] = acc[t][r] + bvv[t];
            }
        }
        __syncthreads();
        {   // P: 256 slots
            int a = tid >> 5, c = tid & 31;
            float sum = 0.f;
            for (int gg = 25 * a; gg < 25 * a + 25; ++gg)
                sum += Vs[(gg >> 3) * 520 + ((gg & 7) << 6) + c];
            P[(size_t)bt * 256 + tid] = sum;
        }
        for (int s = tid; s < 800; s += 256) {   // U: 800 slots
            int jp = s >> 5, c = s & 31;
            float sum = 0.f;
#pragma unroll
            for (int a = 0; a < 8; ++a) {
                int gg = 25 * a + jp;
                sum += Vs[(gg >> 3) * 520 + ((gg & 7) << 6) + 32 + c];
            }
            U[(size_t)bt * 800 + s] = sum;
        }
    }
}

// per (b,to'): conv contraction + masked rank-1 softmax diagonal + output.
// Stages this b's P (16x256) and klow (16x200) in LDS, computes kssum/vssum
// rows for its own `to`, and reads U row-pairs directly for temporal half.
__global__ __launch_bounds__(256) void k_final2(const float* __restrict__ qlow,
                        const float* __restrict__ klow,
                        const float* __restrict__ P, const float* __restrict__ U,
                        const float* __restrict__ Wconv, const float* __restrict__ bconv,
                        const int* __restrict__ mask_s, float* __restrict__ out) {
    __shared__ float Pall[4096];     // P rows b*16+t, t=0..15 (16 KB)
    __shared__ float Kl[3200];       // klow rows b*16+t, t=0..15 (12.8 KB)
    __shared__ float qv[200], kv[200], vsl[8 * 36], dg[200];
    __shared__ float Wc[16];
    __shared__ float bcv;
    __shared__ int msk[625];
    int blk = blockIdx.x;            // b*32 + top
    int b = blk >> 5, top = blk & 31;
    int tid = threadIdx.x;           // 256

    {   // stage
        const float4* Ps = (const float4*)(P + (size_t)b * 4096);
        float4* Pd = (float4*)Pall;
        for (int s = tid; s < 1024; s += 256) Pd[s] = Ps[s];
        const float4* Ks = (const float4*)(klow + (size_t)b * 3200);
        float4* Kd = (float4*)Kl;
        for (int s = tid; s < 800; s += 256) Kd[s] = Ks[s];
        for (int s = tid; s < 625; s += 256) msk[s] = mask_s[top * 625 + s];
        if (tid < 16) Wc[tid] = Wconv[top * 16 + tid];
        if (tid == 0) bcv = bconv[top];
        if (tid < 200) {
            int h = tid / 25, i = tid - 25 * (tid / 25);
            qv[tid] = qlow[((size_t)b * 32 + 4 * h + (top >> 3)) * 200 + 25 * (top & 7) + i];
        }
    }
    __syncthreads();

    {   // vssum row for this to: vsl[h][c], h=tid>>5, c=tid&31 (exactly 256)
        int h = tid >> 5, c = tid & 31;
        float s = 25.f * bcv;
#pragma unroll
        for (int tp = 0; tp < 16; ++tp)
            s += Wc[tp] * Pall[(2 * h + (tp >> 3)) * 256 + (tp & 7) * 32 + c];
        vsl[h * 36 + c] = s;
    }
    if (tid < 200) {   // kssum row for this to: kv[h*25+i]
        int h = tid / 25, i = tid - 25 * (tid / 25);
        float s = 32.f * bcv;
#pragma unroll
        for (int tp = 0; tp < 16; ++tp)
            s += Wc[tp] * Kl[(2 * h + (tp >> 3)) * 200 + 25 * (tp & 7) + i];
        kv[tid] = s;
    }
    __syncthreads();

    if (tid < 200) {   // masked rank-1 softmax diagonal
        int h = tid / 25, i = tid - 25 * (tid / 25);
        float q = qv[tid];
        float m = -3.0e38f;
#pragma unroll
        for (int j = 0; j < 25; ++j) {
            float a = msk[i * 25 + j] ? q * kv[h * 25 + j] : NEGC;
            m = fmaxf(m, a);
        }
        float sum = 0.f;
#pragma unroll
        for (int j = 0; j < 25; ++j) {
            float a = msk[i * 25 + j] ? q * kv[h * 25 + j] : NEGC;
            sum += expf(a - m);
        }
        float ai = msk[i * 25 + i] ? q * kv[h * 25 + i] : NEGC;
        dg[tid] = expf(ai - m) / sum;
    }
    __syncthreads();

    float4* outp = (float4*)(out + (size_t)blk * 12800);
    const float4* U4 = (const float4*)U;
    for (int q = tid; q < 3200; q += 256) {   // q = i*128 + o4
        int i = q >> 7, o4 = q & 127, h = o4 >> 4, e = o4 & 15;
        float4 r;
        if (e < 8) {            // spatial half: c = 4e
            float d = dg[h * 25 + i];
            const float* vp = &vsl[h * 36 + 4 * e];
            r.x = d * vp[0]; r.y = d * vp[1]; r.z = d * vp[2]; r.w = d * vp[3];
        } else {                // temporal half: vt = U[2h] + U[2h+1]
            size_t u0 = ((size_t)b * 16 + 2 * h) * 200 + i * 8 + (e - 8);
            float4 a0 = U4[u0];
            float4 a1 = U4[u0 + 200];
            r.x = a0.x + a1.x; r.y = a0.y + a1.y;
            r.z = a0.z + a1.z; r.w = a0.w + a1.w;
        }
        outp[q] = r;
    }
}

extern "C" void kernel_launch(void* const* d_in, const int* in_sizes, int n_in,
                              void* d_out, int out_size, void* d_ws, size_t ws_size,
                              hipStream_t stream) {
    const float* x      = (const float*)d_in[0];
    const float* enc    = (const float*)d_in[1];
    const int*   mask_s = (const int*)d_in[2];
    // d_in[3] = mask_t: dead
    const float* Wq     = (const float*)d_in[4];
    const float* bq     = (const float*)d_in[5];
    const float* Wk     = (const float*)d_in[6];
    const float* bk     = (const float*)d_in[7];
    const float* Wv     = (const float*)d_in[8];
    const float* bv     = (const float*)d_in[9];
    const float* Wconv  = (const float*)d_in[10];
    const float* bconv  = (const float*)d_in[11];
    float* out = (float*)d_out;
    float* ws  = (float*)d_ws;

    short* Wvb   = (short*)(ws + OFF_WVB);
    float* qlow  = ws + OFF_QLOW;
    float* klow  = ws + OFF_KLOW;
    float* Pbuf  = ws + OFF_P;
    float* Ubuf  = ws + OFF_U;
    // enc in bf16 staged in d_out (209 MB, fully overwritten by k_final2 later)
    short* encb  = (short*)d_out;

    hipLaunchKernelGGL(k_prep, dim3(528), dim3(256), 0, stream,
                       Wq, bq, Wk, bk, Wv, Wvb, ws);
    hipLaunchKernelGGL(k_lowsum2, dim3(3072), dim3(256), 0, stream,
                       x, enc, ws, qlow, klow, encb);
    hipLaunchKernelGGL(k_vgemm, dim3((Bn * Tn) / VG), dim3(256), 0, stream,
                       encb, Wvb, bv, Pbuf, Ubuf);
    hipLaunchKernelGGL(k_final2, dim3(Bn * TOn), dim3(256), 0, stream,
                       qlow, klow, Pbuf, Ubuf, Wconv, bconv, mask_s, out);
}